// Round 1
// 483.965 us; speedup vs baseline: 1.0499x; 1.0499x over previous
//
#include <hip/hip_runtime.h>

// out[b][i][d] = sum_l x_i[b][l][d]
// B=512, D=128, L_i = 64*(i+1) for i=0..7.
//
// R1 design: uniform work decomposition. Every block processes exactly one
// 64-row x 128-col chunk (32 KB) of one (b, i). Total chunks:
//   512 * (1+2+...+8) = 18,432 blocks, all identical cost -> no ragged tail
// (previous version: per-block work spanned 1:8, OccupancyPercent=55%).
//
// Each thread issues 8 INDEPENDENT float4 loads (no loop carrying them, so
// the compiler must keep all 8 in flight; previous version reported
// VGPR_Count=28 < 32 needed, i.e. the unroll was serialized to ~2-3
// outstanding loads). Block-level LDS tree reduce, then one atomicAdd per
// output float (<=8 contenders per address). Output is zeroed by a tiny
// first kernel since the harness poisons the buffer between runs.

struct SumCatArgs {
    const float* x[8];
};

__global__ __launch_bounds__(256) void zero_out_kernel(float4* __restrict__ out) {
    out[(size_t)blockIdx.x * 256 + threadIdx.x] = make_float4(0.f, 0.f, 0.f, 0.f);
}

__global__ __launch_bounds__(256) void fuse_sum_cat_kernel(
    SumCatArgs args, float* __restrict__ out) {
    const int blk = blockIdx.x;

    // Chunk layout: for i in 0..7, for c in 0..i, for b in 0..511.
    // blk = (tri(i) + c) * 512 + b, where tri(i) = i*(i+1)/2.
    const int t = blk >> 9;   // triangular slot 0..35  (tensor i, chunk c)
    const int b = blk & 511;  // batch

    int i = 0;
#pragma unroll
    for (int k = 1; k < 8; ++k) i += (t >= (k * (k + 1)) / 2) ? 1 : 0;
    const int c = t - (i * (i + 1)) / 2;  // 64-row chunk index within tensor i
    const int L = 64 * (i + 1);

    // Base of this chunk: x_i[b][c*64][0], viewed as float4 (32 per row).
    const float4* __restrict__ xr = (const float4*)args.x[i] +
                                    (size_t)b * (size_t)L * 32 +
                                    (size_t)c * (64 * 32);

    const int col = threadIdx.x & 31;  // float4 column 0..31
    const int r   = threadIdx.x >> 5;  // row group 0..7

    // 8 independent loads: rows r, r+8, ..., r+56 of the 64-row chunk.
    // A wave (lanes 0..63) covers two adjacent rows -> 1 KiB contiguous.
    float4 v[8];
#pragma unroll
    for (int u = 0; u < 8; ++u) {
        v[u] = xr[(size_t)(r + u * 8) * 32 + col];
    }

    // Pairwise tree sum of the 8 vectors.
#pragma unroll
    for (int st = 1; st < 8; st <<= 1) {
#pragma unroll
        for (int u = 0; u < 8; u += 2 * st) {
            v[u].x += v[u + st].x;
            v[u].y += v[u + st].y;
            v[u].z += v[u + st].z;
            v[u].w += v[u + st].w;
        }
    }

    __shared__ float4 part[8][32];
    part[r][col] = v[0];
    __syncthreads();

    // 128 threads: one output float each. LDS reads are stride-1 across
    // lanes -> conflict-free. One atomicAdd per float; <=8 contenders.
    const int j = threadIdx.x;
    if (j < 128) {
        const float* pf = (const float*)part;
        float acc = 0.f;
#pragma unroll
        for (int k = 0; k < 8; ++k) acc += pf[k * 128 + j];
        atomicAdd(&out[((size_t)b * 8 + i) * 128 + j], acc);
    }
}

extern "C" void kernel_launch(void* const* d_in, const int* in_sizes, int n_in,
                              void* d_out, int out_size, void* d_ws, size_t ws_size,
                              hipStream_t stream) {
    (void)d_ws; (void)ws_size; (void)in_sizes; (void)n_in;

    SumCatArgs args;
    for (int i = 0; i < 8; ++i) args.x[i] = (const float*)d_in[i];

    // Zero the 2 MiB output (atomic accumulation target). 512*256 float4.
    const int n_f4 = out_size / 16;          // 131072
    zero_out_kernel<<<n_f4 / 256, 256, 0, stream>>>((float4*)d_out);

    // One block per 64-row chunk: 512 * 36 = 18432 blocks.
    fuse_sum_cat_kernel<<<18432, 256, 0, stream>>>(args, (float*)d_out);
}